// Round 4
// baseline (245.204 us; speedup 1.0000x reference)
//
#include <hip/hip_runtime.h>
#include <cstdint>
#include <cmath>

#define QP    127.0f
#define MINR  1e-6f

// Problem dims: B*N = 8192 tokens, D = 1024, H = 4096
#define MTOK 8192
#define DDIM 1024
#define HDIM 4096

typedef __attribute__((ext_vector_type(4))) int int32x4;

__device__ __forceinline__ void gload16(const void* g, void* l) {
    __builtin_amdgcn_global_load_lds(
        (const __attribute__((address_space(1))) void*)g,
        (__attribute__((address_space(3))) void*)l, 16, 0, 0);
}

__global__ void zero_scales_kernel(float* g) {
    if (threadIdx.x < 4) g[threadIdx.x] = 0.0f;
}

// ---- fused 3-tensor absmax: block-range partition, atomicMax per tensor ----
__device__ __forceinline__ float wave_block_max(float m) {
    #pragma unroll
    for (int off = 32; off; off >>= 1) m = fmaxf(m, __shfl_down(m, off));
    __shared__ float sm[4];
    int lane = threadIdx.x & 63, w = threadIdx.x >> 6;
    if (lane == 0) sm[w] = m;
    __syncthreads();
    float bm = 0.0f;
    if (threadIdx.x == 0) bm = fmaxf(fmaxf(sm[0], sm[1]), fmaxf(sm[2], sm[3]));
    return bm;
}

__device__ __forceinline__ void absmax_range(const float4* in4, int n4, int bid, int nb,
                                             float* gout) {
    int tid = bid * blockDim.x + threadIdx.x;
    int stride = nb * blockDim.x;
    float m = 0.0f;
    for (int i = tid; i < n4; i += stride) {
        float4 v = in4[i];
        m = fmaxf(m, fmaxf(fmaxf(fabsf(v.x), fabsf(v.y)), fmaxf(fabsf(v.z), fabsf(v.w))));
    }
    float bm = wave_block_max(m);
    if (threadIdx.x == 0) atomicMax((int*)gout, __float_as_int(bm));
}

// blocks [0,1024) -> x, [1024,1536) -> w1, [1536,2048) -> w2
__global__ void absmax3_kernel(const float* __restrict__ x, const float* __restrict__ w1,
                               const float* __restrict__ w2, float* __restrict__ gmax) {
    int b = blockIdx.x;
    if (b < 1024)      absmax_range((const float4*)x,  MTOK * DDIM / 4, b,        1024, gmax + 0);
    else if (b < 1536) absmax_range((const float4*)w1, HDIM * DDIM / 4, b - 1024,  512, gmax + 1);
    else               absmax_range((const float4*)w2, DDIM * HDIM / 4, b - 1536,  512, gmax + 3);
}

__device__ __forceinline__ void quant_range(const float4* in4, int* out4, int n4,
                                            int bid, int nb, const float* gm) {
    const float s = fmaxf(*gm, MINR) / QP;
    int tid = bid * blockDim.x + threadIdx.x;
    int stride = nb * blockDim.x;
    for (int i = tid; i < n4; i += stride) {
        float4 v = in4[i];
        int q0 = ((int)rintf(v.x / s)) & 255;
        int q1 = ((int)rintf(v.y / s)) & 255;
        int q2 = ((int)rintf(v.z / s)) & 255;
        int q3 = ((int)rintf(v.w / s)) & 255;
        out4[i] = q0 | (q1 << 8) | (q2 << 16) | (q3 << 24);
    }
}

// blocks [0,2048) -> x, [2048,3072) -> w1, [3072,4096) -> w2
__global__ void quant3_kernel(const float* __restrict__ x, const float* __restrict__ w1,
                              const float* __restrict__ w2, int8_t* __restrict__ xq,
                              int8_t* __restrict__ w1q, int8_t* __restrict__ w2q,
                              const float* __restrict__ gmax) {
    int b = blockIdx.x;
    if (b < 2048)      quant_range((const float4*)x,  (int*)xq,  MTOK * DDIM / 4, b,        2048, gmax + 0);
    else if (b < 3072) quant_range((const float4*)w1, (int*)w1q, HDIM * DDIM / 4, b - 2048, 1024, gmax + 1);
    else               quant_range((const float4*)w2, (int*)w2q, DDIM * HDIM / 4, b - 3072, 1024, gmax + 3);
}

__global__ void quant_kernel(const float* __restrict__ in, int8_t* __restrict__ out,
                             int n4, const float* __restrict__ gm) {
    quant_range((const float4*)in, (int*)out, n4, blockIdx.x, gridDim.x, gm);
}

// ---------------------------------------------------------------------------
// 256x128 tile, BK=128 bytes, 4 waves (2M x 2N), per-wave output 128x64,
// acc[8][4] (128 acc regs), mfma_i32_16x16x64_i8.
// Rationale (round-4): per-tile-step cost is dominated by stage-drain+barrier
// (~2700 of ~3337 cyc), paid once per step. Doubling M-tile doubles MFMA work
// per step (64/wave ~ 1300 cyc) at flat drain cost -> ~1.5x better
// amortization, while LDS stays 48 KB (not the m132 64 KB occupancy cliff).
// Natural 2D grid (bc = blockIdx.x fastest): XCD k sees bc = k (mod 8) ->
// B panels pinned per-XCD L2; concurrent blocks share one A panel (round-1
// measured FETCH 39 MB vs 104 MB with br-fastest swizzle -> swizzle reverted).
// ---------------------------------------------------------------------------
template<int KD, int ND, bool GELU_EPI>
__global__ __launch_bounds__(256, 2)
void gemm_i8_kernel(const int8_t* __restrict__ A, const int8_t* __restrict__ B,
                    const float* __restrict__ bias,
                    const float* __restrict__ gmA, const float* __restrict__ gmB,
                    float* __restrict__ out, float* __restrict__ omax) {
    __shared__ int8_t lA[256 * 128];   // 32 KB
    __shared__ int8_t lB[128 * 128];   // 16 KB
    const int t = threadIdx.x;
    const int lane = t & 63;
    const int w = t >> 6;
    const int wm = (w >> 1) * 128;     // wave row offset: 0 / 128
    const int wn = (w & 1) * 64;       // wave col offset: 0 / 64
    const int lr = lane & 15;
    const int lg = lane >> 4;          // 0..3
    const int br = blockIdx.y, bc = blockIdx.x;

    const int8_t* Ab = A + (size_t)br * 256 * KD;
    const int8_t* Bb = B + (size_t)bc * 128 * KD;

    int32x4 acc[8][4] = {};

    for (int kt = 0; kt < KD / 128; ++kt) {
        // stage 32 KB A (2048 x 16B chunks, 8/thread) + 16 KB B (4/thread);
        // linear LDS dest, source slot pre-swizzled by (row&7) (T2 involution)
        #pragma unroll
        for (int i = 0; i < 8; ++i) {
            int c = t + i * 256;          // 0..2047
            int r = c >> 3;               // A row 0..255
            int sl = c & 7;
            int sc = ((sl ^ (r & 7)) << 4);
            gload16(Ab + (size_t)r * KD + kt * 128 + sc, &lA[c * 16]);
        }
        #pragma unroll
        for (int i = 0; i < 4; ++i) {
            int c = t + i * 256;          // 0..1023
            int r = c >> 3;               // B row 0..127
            int sl = c & 7;
            int sc = ((sl ^ (r & 7)) << 4);
            gload16(Bb + (size_t)r * KD + kt * 128 + sc, &lB[c * 16]);
        }
        __syncthreads();

        #pragma unroll
        for (int kk = 0; kk < 2; ++kk) {
            int32x4 af[8], bf[4];
            #pragma unroll
            for (int m = 0; m < 8; ++m) {
                int r = wm + m * 16 + lr;
                int g = kk * 4 + lg;
                af[m] = *(const int32x4*)&lA[r * 128 + ((g ^ (r & 7)) << 4)];
            }
            #pragma unroll
            for (int n = 0; n < 4; ++n) {
                int r = wn + n * 16 + lr;
                int g = kk * 4 + lg;
                bf[n] = *(const int32x4*)&lB[r * 128 + ((g ^ (r & 7)) << 4)];
            }
            #pragma unroll
            for (int m = 0; m < 8; ++m)
                #pragma unroll
                for (int n = 0; n < 4; ++n)
                    acc[m][n] = __builtin_amdgcn_mfma_i32_16x16x64_i8(af[m], bf[n], acc[m][n], 0, 0, 0);
        }
        __syncthreads();
    }

    // epilogue — replicate reference fp32 op order exactly
    const float sA = fmaxf(*gmA, MINR) / QP;
    const float sB = fmaxf(*gmB, MINR) / QP;
    const float s = sB * sA;
    float lmax = 0.0f;
    #pragma unroll
    for (int m = 0; m < 8; ++m) {
        #pragma unroll
        for (int n = 0; n < 4; ++n) {
            #pragma unroll
            for (int r = 0; r < 4; ++r) {
                int row = br * 256 + wm + m * 16 + lg * 4 + r;
                int col = bc * 128 + wn + n * 16 + lr;
                float f = (float)acc[m][n][r] + bias[col];
                f *= s;
                if (GELU_EPI) {
                    float gg = f * (erff(f / 1.41421356237309504880f) + 1.0f) * 0.5f;
                    out[(size_t)row * ND + col] = gg;
                    lmax = fmaxf(lmax, fabsf(gg));
                } else {
                    out[(size_t)row * ND + col] = f;
                }
            }
        }
    }
    if (GELU_EPI) {
        #pragma unroll
        for (int off = 32; off; off >>= 1) lmax = fmaxf(lmax, __shfl_down(lmax, off));
        __shared__ float red[4];
        if (lane == 0) red[w] = lmax;
        __syncthreads();
        if (t == 0) {
            float bm = fmaxf(fmaxf(red[0], red[1]), fmaxf(red[2], red[3]));
            atomicMax((int*)omax, __float_as_int(bm));
        }
    }
}

extern "C" void kernel_launch(void* const* d_in, const int* in_sizes, int n_in,
                              void* d_out, int out_size, void* d_ws, size_t ws_size,
                              hipStream_t stream) {
    const float* x  = (const float*)d_in[0];   // [8192, 1024]
    const float* w1 = (const float*)d_in[1];   // [4096, 1024]
    const float* b1 = (const float*)d_in[2];   // [4096]
    const float* w2 = (const float*)d_in[3];   // [1024, 4096]
    const float* b2 = (const float*)d_in[4];   // [1024]
    float* out = (float*)d_out;                // [8192, 1024]

    uint8_t* ws = (uint8_t*)d_ws;
    float*  gmax = (float*)ws;                           // [0]=x [1]=w1 [2]=h [3]=w2
    int8_t* xq   = (int8_t*)(ws + 256);
    int8_t* w1q  = xq  + (size_t)MTOK * DDIM;
    int8_t* w2q  = w1q + (size_t)HDIM * DDIM;
    int8_t* hq   = w2q + (size_t)DDIM * HDIM;
    float*  h    = (float*)(hq + (size_t)MTOK * HDIM);   // 128 MiB fp32

    zero_scales_kernel<<<1, 64, 0, stream>>>(gmax);

    absmax3_kernel<<<2048, 256, 0, stream>>>(x, w1, w2, gmax);
    quant3_kernel<<<4096, 256, 0, stream>>>(x, w1, w2, xq, w1q, w2q, gmax);

    // h = gelu((xq @ w1q^T + b1) * s1), fused absmax(h) -> gmax[2]
    // grid = (4096/128, 8192/256) = (32, 32) = 1024 blocks
    gemm_i8_kernel<DDIM, HDIM, true>
        <<<dim3(32, 32), 256, 0, stream>>>(xq, w1q, b1, gmax + 0, gmax + 1, h, gmax + 2);

    quant_kernel<<<4096, 256, 0, stream>>>(h, hq, MTOK * HDIM / 4, gmax + 2);

    // out = (hq @ w2q^T + b2) * s2 ; grid = (1024/128, 8192/256) = (8, 32) = 256 blocks
    gemm_i8_kernel<HDIM, DDIM, false>
        <<<dim3(8, 32), 256, 0, stream>>>(hq, w2q, b2, gmax + 2, gmax + 3, out, nullptr);
}